// Round 2
// baseline (182.376 us; speedup 1.0000x reference)
//
#include <hip/hip_runtime.h>
#include <math.h>

// Problem constants (from reference): D=8, H=64, W=64 -> 32768 pixels, 1024 gaussians
#define NG    1024
#define KD    256        // representation feature dim
#define NPIX  32768      // D*H*W
#define BLOCK 512
#define PT    64         // NPIX / BLOCK pixels per thread

// 1.5 * ln(2*pi)
#define C_15_LOG2PI 2.7568155996140185f

__device__ __forceinline__ float softplus_f(float x) {
    // stable: max(x,0) + log1p(exp(-|x|)) — matches jax.nn.softplus
    return fmaxf(x, 0.0f) + log1pf(expf(-fabsf(x)));
}

// Recompute-everywhere design: the per-pixel log-prob costs ~8 VALU + 1 exp,
// so we recompute it in each of the 3 passes instead of caching 64 floats in
// registers (round-1 version spilled / killed occupancy -> 151 us).
// VGPR stays ~40 -> 8 waves/SIMD -> 4 blocks/CU -> all 1024 blocks in one round.
__global__ __launch_bounds__(BLOCK, 8)
void mvn_profile_kernel(const float* __restrict__ rep,
                        const float* __restrict__ mean_W,
                        const float* __restrict__ mean_b,
                        const float* __restrict__ scale_W,
                        const float* __restrict__ scale_b,
                        float* __restrict__ out)
{
    const int g = blockIdx.x;   // one block per gaussian
    const int t = threadIdx.x;

    __shared__ float s_part[9][4];  // per-wave partials for the 9 dot products
    __shared__ float s_par[10];     // broadcast: mx,my,mz, r00,L10,r11,L20,L21,r22, c
    __shared__ float s_red[8];      // per-wave reduction scratch (8 waves)

    // ---- prelude: 9 dot-products of length 256 (threads 0..255 = waves 0..3) ----
    if (t < KD) {
        float r = rep[g * KD + t];
        float acc[9];
        #pragma unroll
        for (int k = 0; k < 3; ++k) acc[k]     = r * mean_W[k * KD + t];
        #pragma unroll
        for (int k = 0; k < 6; ++k) acc[3 + k] = r * scale_W[k * KD + t];
        #pragma unroll
        for (int k = 0; k < 9; ++k) {
            float v = acc[k];
            #pragma unroll
            for (int off = 32; off >= 1; off >>= 1)
                v += __shfl_xor(v, off, 64);
            if ((t & 63) == 0) s_part[k][t >> 6] = v;
        }
    }
    __syncthreads();
    if (t == 0) {
        float dsum[9];
        #pragma unroll
        for (int k = 0; k < 9; ++k)
            dsum[k] = (s_part[k][0] + s_part[k][1]) + (s_part[k][2] + s_part[k][3]);
        float mx = dsum[0] + mean_b[0];
        float my = dsum[1] + mean_b[1];
        float mz = dsum[2] + mean_b[2];
        float s0 = softplus_f(dsum[3] + scale_b[0]) + 1e-6f;
        float s1 = softplus_f(dsum[4] + scale_b[1]) + 1e-6f;
        float s2 = softplus_f(dsum[5] + scale_b[2]) + 1e-6f;
        float s3 = softplus_f(dsum[6] + scale_b[3]) + 1e-6f;
        float s4 = softplus_f(dsum[7] + scale_b[4]) + 1e-6f;
        float s5 = softplus_f(dsum[8] + scale_b[5]) + 1e-6f;
        float L00 = softplus_f(s0);
        float L11 = softplus_f(s2);
        float L22 = softplus_f(s5);
        s_par[0] = mx; s_par[1] = my; s_par[2] = mz;
        s_par[3] = 1.0f / L00;
        s_par[4] = s1;                // L10
        s_par[5] = 1.0f / L11;
        s_par[6] = s3;                // L20
        s_par[7] = s4;                // L21
        s_par[8] = 1.0f / L22;
        s_par[9] = logf(L00) + logf(L11) + logf(L22) + C_15_LOG2PI;
    }
    __syncthreads();
    const float mx  = s_par[0], my  = s_par[1], mz  = s_par[2];
    const float r00 = s_par[3], L10 = s_par[4], r11 = s_par[5];
    const float L20 = s_par[6], L21 = s_par[7], r22 = s_par[8];
    const float c   = s_par[9];

    // ---- thread-constant x-part: pixel p = t + 512*i -> x index = t & 63 fixed ----
    const float px    = (float)(t & 63) - 31.5f;
    const float y0    = (px - mx) * r00;
    const float negc2 = -(c + 0.5f * y0 * y0);        // folds y0^2 into the constant
    const float dyoff = -31.5f - my - L10 * y0;       // y1 = (fy + dyoff) * r11
    const float dzoff = -3.5f  - mz - L20 * y0;       // y2 = (fz + dzoff - L21*y1) * r22
    const int   jbase = t >> 6;                       // 0..7; j = p/64 = jbase + 8*i

    // ---- pass A: max of log-probs (recompute, nothing cached) ----
    float lmax = -3.4e38f;
    #pragma unroll
    for (int i = 0; i < PT; ++i) {
        float fy = (float)(jbase + 8 * (i & 7));   // j & 63
        float fz = (float)(i >> 3);                // j >> 6
        float y1 = (fy + dyoff) * r11;
        float w  = fz + dzoff - L21 * y1;
        float y2 = w * r22;
        float q  = y1 * y1 + y2 * y2;
        float v  = fmaf(-0.5f, q, negc2);
        lmax = fmaxf(lmax, v);
    }
    #pragma unroll
    for (int off = 32; off >= 1; off >>= 1)
        lmax = fmaxf(lmax, __shfl_xor(lmax, off, 64));
    if ((t & 63) == 0) s_red[t >> 6] = lmax;
    __syncthreads();
    float m = s_red[0];
    #pragma unroll
    for (int k = 1; k < 8; ++k) m = fmaxf(m, s_red[k]);

    // ---- pass B: sum of exp(lp - m) (recompute) ----
    const float negc2m = negc2 - m;
    float lsum = 0.0f;
    #pragma unroll
    for (int i = 0; i < PT; ++i) {
        float fy = (float)(jbase + 8 * (i & 7));
        float fz = (float)(i >> 3);
        float y1 = (fy + dyoff) * r11;
        float w  = fz + dzoff - L21 * y1;
        float y2 = w * r22;
        float q  = y1 * y1 + y2 * y2;
        float v  = fmaf(-0.5f, q, negc2m);
        lsum += __expf(v);
    }
    #pragma unroll
    for (int off = 32; off >= 1; off >>= 1)
        lsum += __shfl_xor(lsum, off, 64);
    __syncthreads();               // s_red reuse barrier (all reads of max done)
    if ((t & 63) == 0) s_red[t >> 6] = lsum;
    __syncthreads();
    float S = 0.0f;
    #pragma unroll
    for (int k = 0; k < 8; ++k) S += s_red[k];
    const float scale = 1.0f / (S + 1e-10f);

    // ---- pass C: recompute exp, scale, single coalesced store ----
    float* op = out + (size_t)g * NPIX + t;
    #pragma unroll
    for (int i = 0; i < PT; ++i) {
        float fy = (float)(jbase + 8 * (i & 7));
        float fz = (float)(i >> 3);
        float y1 = (fy + dyoff) * r11;
        float w  = fz + dzoff - L21 * y1;
        float y2 = w * r22;
        float q  = y1 * y1 + y2 * y2;
        float v  = fmaf(-0.5f, q, negc2m);
        op[i * BLOCK] = __expf(v) * scale;
    }
}

extern "C" void kernel_launch(void* const* d_in, const int* in_sizes, int n_in,
                              void* d_out, int out_size, void* d_ws, size_t ws_size,
                              hipStream_t stream) {
    const float* rep     = (const float*)d_in[0];
    const float* mean_W  = (const float*)d_in[1];
    const float* mean_b  = (const float*)d_in[2];
    const float* scale_W = (const float*)d_in[3];
    const float* scale_b = (const float*)d_in[4];
    float* out = (float*)d_out;

    hipLaunchKernelGGL(mvn_profile_kernel, dim3(NG), dim3(BLOCK), 0, stream,
                       rep, mean_W, mean_b, scale_W, scale_b, out);
}

// Round 3
// 169.721 us; speedup vs baseline: 1.0746x; 1.0746x over previous
//
#include <hip/hip_runtime.h>
#include <math.h>

// Problem constants (from reference): D=8, H=64, W=64 -> 32768 pixels, 1024 gaussians
#define NG    1024
#define KD    256        // representation feature dim
#define NPIX  32768      // D*H*W
#define BLOCK 512

#define LN2PI_15  2.7568155996140185f   // 1.5 * ln(2*pi)
#define LOG2E     1.4426950408889634f
#define SQH_L2E   0.8493218f            // sqrt(0.5 * log2(e))

__device__ __forceinline__ float softplus_f(float x) {
    // stable: max(x,0) + log1p(exp(-|x|)) — matches jax.nn.softplus
    return fmaxf(x, 0.0f) + log1pf(expf(-fabsf(x)));
}

__device__ __forceinline__ float exp2_fast(float x) {
#if __has_builtin(__builtin_amdgcn_exp2f)
    return __builtin_amdgcn_exp2f(x);     // v_exp_f32
#else
    float r; asm("v_exp_f32 %0, %1" : "=v"(r) : "v"(x)); return r;
#endif
}

// Design notes (R3):
//  - NO max pass: L >= softplus(1e-6) ~= 0.693 => logdet >= -1.1 => lp <= -1.66,
//    so exp(lp) never overflows; max-shift cancels in normalization (eps term
//    differs by e^m ~ 0.05x, negligible vs sum >= 6e-3). 2 passes total.
//  - exp2 domain: Cholesky solves pre-scaled by sqrt(0.5*log2e) so the per-pixel
//    body is y2s=fma, v2=fma(-y2s,y2s,base), exp2. -log2(S+1e-10) folded into
//    base[] between passes => pass 2 has no normalize mul.
//  - thread t owns pixels 4t+k+2048i (k<4, i<16): float4 stores (1KB/wave-instr),
//    only 2 distinct y-rows and 8 z-planes per thread => 16 precomputed consts.
__global__ __launch_bounds__(BLOCK, 8)
void mvn_profile_kernel(const float* __restrict__ rep,
                        const float* __restrict__ mean_W,
                        const float* __restrict__ mean_b,
                        const float* __restrict__ scale_W,
                        const float* __restrict__ scale_b,
                        float* __restrict__ out)
{
    const int g = blockIdx.x;   // one block per gaussian
    const int t = threadIdx.x;

    __shared__ float s_part[9][4];  // per-wave partials for the 9 dot products
    __shared__ float s_par[10];     // mx,my,mz, r00,L10,r11,L20,L21,r22s, c0
    __shared__ float s_red[8];      // per-wave reduction scratch (8 waves)

    // ---- prelude: 9 dot-products of length 256 (threads 0..255 = waves 0..3) ----
    if (t < KD) {
        float r = rep[g * KD + t];
        float acc9[9];
        #pragma unroll
        for (int k = 0; k < 3; ++k) acc9[k]     = r * mean_W[k * KD + t];
        #pragma unroll
        for (int k = 0; k < 6; ++k) acc9[3 + k] = r * scale_W[k * KD + t];
        #pragma unroll
        for (int k = 0; k < 9; ++k) {
            float v = acc9[k];
            #pragma unroll
            for (int off = 32; off >= 1; off >>= 1)
                v += __shfl_xor(v, off, 64);
            if ((t & 63) == 0) s_part[k][t >> 6] = v;
        }
    }
    __syncthreads();
    if (t == 0) {
        float dsum[9];
        #pragma unroll
        for (int k = 0; k < 9; ++k)
            dsum[k] = (s_part[k][0] + s_part[k][1]) + (s_part[k][2] + s_part[k][3]);
        float mx = dsum[0] + mean_b[0];
        float my = dsum[1] + mean_b[1];
        float mz = dsum[2] + mean_b[2];
        float s0 = softplus_f(dsum[3] + scale_b[0]) + 1e-6f;
        float s1 = softplus_f(dsum[4] + scale_b[1]) + 1e-6f;
        float s2 = softplus_f(dsum[5] + scale_b[2]) + 1e-6f;
        float s3 = softplus_f(dsum[6] + scale_b[3]) + 1e-6f;
        float s4 = softplus_f(dsum[7] + scale_b[4]) + 1e-6f;
        float s5 = softplus_f(dsum[8] + scale_b[5]) + 1e-6f;
        float L00 = softplus_f(s0);
        float L11 = softplus_f(s2);
        float L22 = softplus_f(s5);
        s_par[0] = mx; s_par[1] = my; s_par[2] = mz;
        s_par[3] = 1.0f / L00;
        s_par[4] = s1;                          // L10
        s_par[5] = 1.0f / L11;
        s_par[6] = s3;                          // L20
        s_par[7] = s4;                          // L21
        s_par[8] = SQH_L2E / L22;               // r22s = sqrt(0.5*log2e)/L22
        // c0 = log2e * (-logdet - 1.5*ln(2pi))
        s_par[9] = -LOG2E * (logf(L00) + logf(L11) + logf(L22) + LN2PI_15);
    }
    __syncthreads();
    const float mx   = s_par[0], my  = s_par[1], mz  = s_par[2];
    const float r00  = s_par[3], L10 = s_par[4], r11 = s_par[5];
    const float L20  = s_par[6], L21 = s_par[7], r22s = s_par[8];
    const float c0   = s_par[9];
    const float mzc  = -3.5f - mz;              // pz = fz - 3.5

    // ---- per-thread constants: k=0..3 (x = 4*(t&15)+k), fsel=0/1 (fy = (t>>4)+32*fsel)
    const float xb = (float)(4 * (t & 15)) - 31.5f - mx;
    const float f0 = (float)(t >> 4);
    float urs[8], base[8];                      // idx = k*2 + fsel
    #pragma unroll
    for (int k = 0; k < 4; ++k) {
        float y0  = (xb + (float)k) * r00;
        float y0s = y0 * SQH_L2E;
        float b0  = fmaf(-y0s, y0s, c0);
        float dzk = fmaf(-L20, y0, mzc);        // -3.5 - mz - L20*y0
        float dyk = fmaf(-L10, y0, -31.5f - my);
        #pragma unroll
        for (int f = 0; f < 2; ++f) {
            float py  = f0 + (float)(32 * f);
            float y1  = (py + dyk) * r11;
            float y1s = y1 * SQH_L2E;
            base[k*2+f] = fmaf(-y1s, y1s, b0);
            urs [k*2+f] = fmaf(-L21, y1, dzk) * r22s;
        }
    }

    // ---- pass 1: sum of exp2(v2) over this thread's 64 pixels ----
    float acc0 = 0.f, acc1 = 0.f, acc2 = 0.f, acc3 = 0.f;
    #pragma unroll
    for (int i = 0; i < 16; ++i) {
        const int   fs = i & 1;
        const float fz = (float)(i >> 1);
        {
            float y2s = fmaf(fz, r22s, urs[0*2+fs]);
            acc0 += exp2_fast(fmaf(-y2s, y2s, base[0*2+fs]));
        }
        {
            float y2s = fmaf(fz, r22s, urs[1*2+fs]);
            acc1 += exp2_fast(fmaf(-y2s, y2s, base[1*2+fs]));
        }
        {
            float y2s = fmaf(fz, r22s, urs[2*2+fs]);
            acc2 += exp2_fast(fmaf(-y2s, y2s, base[2*2+fs]));
        }
        {
            float y2s = fmaf(fz, r22s, urs[3*2+fs]);
            acc3 += exp2_fast(fmaf(-y2s, y2s, base[3*2+fs]));
        }
    }
    float lsum = (acc0 + acc1) + (acc2 + acc3);
    #pragma unroll
    for (int off = 32; off >= 1; off >>= 1)
        lsum += __shfl_xor(lsum, off, 64);
    if ((t & 63) == 0) s_red[t >> 6] = lsum;
    __syncthreads();
    float S = 0.0f;
    #pragma unroll
    for (int k = 0; k < 8; ++k) S += s_red[k];

    // fold normalization into the exponent: out = exp2(v2 - log2(S + 1e-10))
    const float lS = log2f(S + 1e-10f);
    #pragma unroll
    for (int k = 0; k < 8; ++k) base[k] -= lS;

    // ---- pass 2: recompute, exp2, float4 store (wave writes 1KB/instr) ----
    float4* op4 = (float4*)(out + (size_t)g * NPIX) + t;
    #pragma unroll
    for (int i = 0; i < 16; ++i) {
        const int   fs = i & 1;
        const float fz = (float)(i >> 1);
        float4 o;
        { float y2s = fmaf(fz, r22s, urs[0*2+fs]); o.x = exp2_fast(fmaf(-y2s, y2s, base[0*2+fs])); }
        { float y2s = fmaf(fz, r22s, urs[1*2+fs]); o.y = exp2_fast(fmaf(-y2s, y2s, base[1*2+fs])); }
        { float y2s = fmaf(fz, r22s, urs[2*2+fs]); o.z = exp2_fast(fmaf(-y2s, y2s, base[2*2+fs])); }
        { float y2s = fmaf(fz, r22s, urs[3*2+fs]); o.w = exp2_fast(fmaf(-y2s, y2s, base[3*2+fs])); }
        op4[i * 512] = o;    // pixel block p = 4t + 2048*i
    }
}

extern "C" void kernel_launch(void* const* d_in, const int* in_sizes, int n_in,
                              void* d_out, int out_size, void* d_ws, size_t ws_size,
                              hipStream_t stream) {
    const float* rep     = (const float*)d_in[0];
    const float* mean_W  = (const float*)d_in[1];
    const float* mean_b  = (const float*)d_in[2];
    const float* scale_W = (const float*)d_in[3];
    const float* scale_b = (const float*)d_in[4];
    float* out = (float*)d_out;

    hipLaunchKernelGGL(mvn_profile_kernel, dim3(NG), dim3(BLOCK), 0, stream,
                       rep, mean_W, mean_b, scale_W, scale_b, out);
}

// Round 4
// 151.675 us; speedup vs baseline: 1.2024x; 1.1190x over previous
//
#include <hip/hip_runtime.h>
#include <math.h>

// Problem constants (from reference): D=8, H=64, W=64 -> 32768 pixels, 1024 gaussians
#define NG    1024
#define KD    256        // representation feature dim
#define NPIX  32768      // D*H*W
#define BLOCK 512

#define LN2PI_15  2.7568155996140185f   // 1.5 * ln(2*pi)
#define LOG2E     1.4426950408889634f
#define SQH_L2E   0.8493218f            // sqrt(0.5 * log2(e))

__device__ __forceinline__ float softplus_f(float x) {
    // stable: max(x,0) + log1p(exp(-|x|)) — matches jax.nn.softplus
    return fmaxf(x, 0.0f) + log1pf(expf(-fabsf(x)));
}

__device__ __forceinline__ float exp2_fast(float x) {
#if __has_builtin(__builtin_amdgcn_exp2f)
    return __builtin_amdgcn_exp2f(x);     // v_exp_f32
#else
    float r; asm("v_exp_f32 %0, %1" : "=v"(r) : "v"(x)); return r;
#endif
}

// R4 design: compute exp ONCE per pixel, cache in registers (64 floats/thread),
// then scale+store. R1 showed the cached structure is fastest but its register
// allocation was unpinned (spills / low occupancy); R3 showed recomputing exp
// costs ~18us/pass. Here: __launch_bounds__(512,4) => 128-VGPR budget, peak
// live state ~100 VGPR (ec[64]+urs[8]+base[8]+temps) => no spill, 4 waves/SIMD.
//  - NO max pass: L>=log2 => lp<=-1.66, exp never overflows; max-shift cancels
//    in normalization (verified: absmax 2.4e-4 in R3).
//  - exp2 domain: solves pre-scaled by sqrt(0.5*log2e); per-pixel pass-1 body
//    is fma, fma, exp2, add.
//  - thread t owns pixels 4t+k+2048i (k<4,i<16): 16 float4 stores/thread,
//    each wave instr writes 1KB contiguous.
__global__ __launch_bounds__(BLOCK, 4)
void mvn_profile_kernel(const float* __restrict__ rep,
                        const float* __restrict__ mean_W,
                        const float* __restrict__ mean_b,
                        const float* __restrict__ scale_W,
                        const float* __restrict__ scale_b,
                        float* __restrict__ out)
{
    const int g = blockIdx.x;   // one block per gaussian
    const int t = threadIdx.x;

    __shared__ float s_part[9][4];  // per-wave partials for the 9 dot products
    __shared__ float s_par[10];     // mx,my,mz, r00,L10,r11,L20,L21,r22s, c0
    __shared__ float s_red[8];      // per-wave reduction scratch (8 waves)

    // ---- prelude: 9 dot-products of length 256 (threads 0..255 = waves 0..3) ----
    if (t < KD) {
        float r = rep[g * KD + t];
        float acc9[9];
        #pragma unroll
        for (int k = 0; k < 3; ++k) acc9[k]     = r * mean_W[k * KD + t];
        #pragma unroll
        for (int k = 0; k < 6; ++k) acc9[3 + k] = r * scale_W[k * KD + t];
        #pragma unroll
        for (int k = 0; k < 9; ++k) {
            float v = acc9[k];
            #pragma unroll
            for (int off = 32; off >= 1; off >>= 1)
                v += __shfl_xor(v, off, 64);
            if ((t & 63) == 0) s_part[k][t >> 6] = v;
        }
    }
    __syncthreads();
    if (t == 0) {
        float dsum[9];
        #pragma unroll
        for (int k = 0; k < 9; ++k)
            dsum[k] = (s_part[k][0] + s_part[k][1]) + (s_part[k][2] + s_part[k][3]);
        float mx = dsum[0] + mean_b[0];
        float my = dsum[1] + mean_b[1];
        float mz = dsum[2] + mean_b[2];
        float s0 = softplus_f(dsum[3] + scale_b[0]) + 1e-6f;
        float s1 = softplus_f(dsum[4] + scale_b[1]) + 1e-6f;
        float s2 = softplus_f(dsum[5] + scale_b[2]) + 1e-6f;
        float s3 = softplus_f(dsum[6] + scale_b[3]) + 1e-6f;
        float s4 = softplus_f(dsum[7] + scale_b[4]) + 1e-6f;
        float s5 = softplus_f(dsum[8] + scale_b[5]) + 1e-6f;
        float L00 = softplus_f(s0);
        float L11 = softplus_f(s2);
        float L22 = softplus_f(s5);
        s_par[0] = mx; s_par[1] = my; s_par[2] = mz;
        s_par[3] = 1.0f / L00;
        s_par[4] = s1;                          // L10
        s_par[5] = 1.0f / L11;
        s_par[6] = s3;                          // L20
        s_par[7] = s4;                          // L21
        s_par[8] = SQH_L2E / L22;               // r22s = sqrt(0.5*log2e)/L22
        // c0 = log2e * (-logdet - 1.5*ln(2pi))
        s_par[9] = -LOG2E * (logf(L00) + logf(L11) + logf(L22) + LN2PI_15);
    }
    __syncthreads();
    const float mx   = s_par[0], my  = s_par[1], mz  = s_par[2];
    const float r00  = s_par[3], L10 = s_par[4], r11 = s_par[5];
    const float L20  = s_par[6], L21 = s_par[7], r22s = s_par[8];
    const float c0   = s_par[9];
    const float mzc  = -3.5f - mz;              // pz = fz - 3.5

    // ---- per-thread constants: k=0..3 (x = 4*(t&15)+k), fsel=0/1 (fy = (t>>4)+32*fsel)
    const float xb = (float)(4 * (t & 15)) - 31.5f - mx;
    const float f0 = (float)(t >> 4);
    float urs[8], base[8];                      // idx = k*2 + fsel
    #pragma unroll
    for (int k = 0; k < 4; ++k) {
        float y0  = (xb + (float)k) * r00;
        float y0s = y0 * SQH_L2E;
        float b0  = fmaf(-y0s, y0s, c0);
        float dzk = fmaf(-L20, y0, mzc);        // -3.5 - mz - L20*y0
        float dyk = fmaf(-L10, y0, -31.5f - my);
        #pragma unroll
        for (int f = 0; f < 2; ++f) {
            float py  = f0 + (float)(32 * f);
            float y1  = (py + dyk) * r11;
            float y1s = y1 * SQH_L2E;
            base[k*2+f] = fmaf(-y1s, y1s, b0);
            urs [k*2+f] = fmaf(-L21, y1, dzk) * r22s;
        }
    }

    // ---- pass 1: exp ONCE per pixel, cache in registers, accumulate sum ----
    float ec[64];                 // the register cache: 64 VGPRs
    float acc0 = 0.f, acc1 = 0.f, acc2 = 0.f, acc3 = 0.f;
    #pragma unroll
    for (int i = 0; i < 16; ++i) {
        const int   fs = i & 1;
        const float fz = (float)(i >> 1);
        {
            float y2s = fmaf(fz, r22s, urs[0*2+fs]);
            float e   = exp2_fast(fmaf(-y2s, y2s, base[0*2+fs]));
            ec[i*4+0] = e; acc0 += e;
        }
        {
            float y2s = fmaf(fz, r22s, urs[1*2+fs]);
            float e   = exp2_fast(fmaf(-y2s, y2s, base[1*2+fs]));
            ec[i*4+1] = e; acc1 += e;
        }
        {
            float y2s = fmaf(fz, r22s, urs[2*2+fs]);
            float e   = exp2_fast(fmaf(-y2s, y2s, base[2*2+fs]));
            ec[i*4+2] = e; acc2 += e;
        }
        {
            float y2s = fmaf(fz, r22s, urs[3*2+fs]);
            float e   = exp2_fast(fmaf(-y2s, y2s, base[3*2+fs]));
            ec[i*4+3] = e; acc3 += e;
        }
    }
    float lsum = (acc0 + acc1) + (acc2 + acc3);
    #pragma unroll
    for (int off = 32; off >= 1; off >>= 1)
        lsum += __shfl_xor(lsum, off, 64);
    if ((t & 63) == 0) s_red[t >> 6] = lsum;
    __syncthreads();
    float S = 0.0f;
    #pragma unroll
    for (int k = 0; k < 8; ++k) S += s_red[k];
    const float scale = 1.0f / (S + 1e-10f);

    // ---- pass 2: scale cached values, float4 store (1KB per wave instr) ----
    float4* op4 = (float4*)(out + (size_t)g * NPIX) + t;
    #pragma unroll
    for (int i = 0; i < 16; ++i) {
        float4 o;
        o.x = ec[i*4+0] * scale;
        o.y = ec[i*4+1] * scale;
        o.z = ec[i*4+2] * scale;
        o.w = ec[i*4+3] * scale;
        op4[i * 512] = o;    // pixel block p = 4t + 2048*i
    }
}

extern "C" void kernel_launch(void* const* d_in, const int* in_sizes, int n_in,
                              void* d_out, int out_size, void* d_ws, size_t ws_size,
                              hipStream_t stream) {
    const float* rep     = (const float*)d_in[0];
    const float* mean_W  = (const float*)d_in[1];
    const float* mean_b  = (const float*)d_in[2];
    const float* scale_W = (const float*)d_in[3];
    const float* scale_b = (const float*)d_in[4];
    float* out = (float*)d_out;

    hipLaunchKernelGGL(mvn_profile_kernel, dim3(NG), dim3(BLOCK), 0, stream,
                       rep, mean_W, mean_b, scale_W, scale_b, out);
}